// Round 4
// baseline (190.112 us; speedup 1.0000x reference)
//
#include <hip/hip_runtime.h>
#include <stdint.h>

// Problem constants (from reference)
#define B_SZ   512
#define T_SZ   100
#define NPRE   256
#define NPOST  256
#define KTOT   (B_SZ * T_SZ)   // 51200

typedef __bf16 bf16x8 __attribute__((ext_vector_type(8)));
typedef float  floatx4 __attribute__((ext_vector_type(4)));

__device__ __forceinline__ uint32_t bf16_rne(float v) {
    uint32_t bits = __float_as_uint(v);
    return (bits + 0x7FFFu + ((bits >> 16) & 1u)) >> 16;
}
__device__ __forceinline__ uint32_t pack_trunc2(float a, float b) {
    return (__float_as_uint(a) >> 16) | (__float_as_uint(b) & 0xFFFF0000u);
}

// ---------------------------------------------------------------------------
// R15 = R10 (proven 43.5 us) + forced deep load pipelining.
// Evidence: R10 is ~85k cycles of stall (VALU 12%, MFMA 7%, conflicts 0);
// R12-R14 VGPR=60-64 vs 48-float source arrays proves the compiler sinks
// loads to uses (just-in-time), so batch-issue depth never existed in the
// emitted code. Fix: (a) double-buffer scan load batches, (b) hoist B loads
// one phase early / next round's scan loads across MFMA1 (T14),
// (c) sched_barrier(0) after each issue cluster pins loads high,
// (d) amdgpu_waves_per_eu(2): allocator may use ~256 VGPR (occupancy is
// LDS-capped at 2 blocks/CU = 8 waves/CU anyway).
// Mapping, LDS layout, arithmetic order, partial layout, reduces: bit-
// identical to R10.
// ---------------------------------------------------------------------------
__device__ __forceinline__ void issue_x(const float* src, int tbase, int n, float* x) {
#pragma unroll
    for (int j = 0; j < n; ++j)
        x[j] = src[(size_t)(tbase + j) * NPRE];
}

__device__ __forceinline__ void consume16(const float* x, float& carry,
                                          uint32_t* pkc, float decay) {
#pragma unroll
    for (int j = 0; j < 16; ++j) {
        uint32_t lo = bf16_rne(carry);   // trace[t]=carry, then update
        carry = decay * (carry + x[2 * j]);
        uint32_t hi = bf16_rne(carry);
        carry = decay * (carry + x[2 * j + 1]);
        pkc[j] = lo | (hi << 16);
    }
}

__device__ __forceinline__ void deposit_A(unsigned short (*A)[512],
                                          const uint32_t* pk, int pg, int lp)
{
#pragma unroll
    for (int kc = 0; kc < 3; ++kc)
#pragma unroll
        for (int w = 0; w < 4; ++w)
            *(uint4*)&A[kc * 8 + pg][(w * 16 + lp) * 8] =
                make_uint4(pk[kc * 16 + w * 4],     pk[kc * 16 + w * 4 + 1],
                           pk[kc * 16 + w * 4 + 2], pk[kc * 16 + w * 4 + 3]);
    // kc = 3: t 96..99 real, 100..127 zero
    *(uint4*)&A[24 + pg][lp * 8] = make_uint4(pk[48], pk[49], 0u, 0u);
#pragma unroll
    for (int w = 1; w < 4; ++w)
        *(uint4*)&A[24 + pg][(w * 16 + lp) * 8] = make_uint4(0u, 0u, 0u, 0u);
}

// B staging split: LOAD issues early (regs), STORE packs late (R10's exact
// pack/store code). half==0 -> t 0..47 (48 loads); half==1 -> t 48..99 (52).
__device__ __forceinline__ void load_B(const float* pb, int half, float* x) {
    if (half == 0) {
#pragma unroll
        for (int j = 0; j < 48; ++j)
            x[j] = pb[(size_t)j * NPOST];
    } else {
#pragma unroll
        for (int j = 0; j < 52; ++j)
            x[j] = pb[(size_t)(48 + j) * NPOST];
    }
}
__device__ __forceinline__ void store_B(unsigned short (*Bl)[512], int half,
                                        int qg, int q15, const float* x)
{
    if (half == 0) {
#pragma unroll
        for (int o = 0; o < 6; ++o)   // octs 0..5: t 0..47
            *(uint4*)&Bl[(o >> 2) * 8 + qg][((o & 3) * 16 + q15) * 8] =
                make_uint4(pack_trunc2(x[o * 8 + 0], x[o * 8 + 1]),
                           pack_trunc2(x[o * 8 + 2], x[o * 8 + 3]),
                           pack_trunc2(x[o * 8 + 4], x[o * 8 + 5]),
                           pack_trunc2(x[o * 8 + 6], x[o * 8 + 7]));
    } else {
#pragma unroll
        for (int o = 6; o < 12; ++o) {  // octs 6..11: t 48..95
            int u = o * 8 - 48;
            *(uint4*)&Bl[(o >> 2) * 8 + qg][((o & 3) * 16 + q15) * 8] =
                make_uint4(pack_trunc2(x[u + 0], x[u + 1]),
                           pack_trunc2(x[u + 2], x[u + 3]),
                           pack_trunc2(x[u + 4], x[u + 5]),
                           pack_trunc2(x[u + 6], x[u + 7]));
        }
        // oct 12: t 96..99 real + zeros; octs 13..15: zero
        *(uint4*)&Bl[24 + qg][q15 * 8] =
            make_uint4(pack_trunc2(x[48], x[49]), pack_trunc2(x[50], x[51]), 0u, 0u);
#pragma unroll
        for (int o = 13; o < 16; ++o)
            *(uint4*)&Bl[24 + qg][((o & 3) * 16 + q15) * 8] =
                make_uint4(0u, 0u, 0u, 0u);
    }
}

__global__ __launch_bounds__(256) __attribute__((amdgpu_waves_per_eu(2)))
void stdp_fused_gemm(
    const float* __restrict__ pre, const float* __restrict__ post,
    float* __restrict__ partial)
{
    __shared__ __align__(16) unsigned short A_lds[32][512];  // 32 KB
    __shared__ __align__(16) unsigned short B_lds[32][512];  // 32 KB

    const int bx   = blockIdx.x;      // 0..511
    const int s    = bx & 127;
    const int tile = bx >> 7;         // 0..3
    const int pt   = tile & 1;
    const int qt   = tile >> 1;
    const int tid  = threadIdx.x;     // 0..255
    const int lane = tid & 63, wave = tid >> 6;   // wave = wp (0..3)
    const int l15 = lane & 15, l4 = lane >> 4;

    const int half  = tid >> 7;       // 0/1 (wave-uniform): scan batch / B t-half
    const int p_loc = tid & 127;      // scan row
    const int qloc  = tid & 127;      // B column
    const int qg = qloc >> 4, q15 = qloc & 15;
    const int pg = p_loc >> 4, lp = p_loc & 15;

    const float decay = 0.95122942450071400910f;   // expf(-1/20)

    floatx4 acc[2][8] = {};

    float x0[32], x1[32], x2[36], xb[52];
    uint32_t pk[50];

    // ---- initial scan-load issue for round 0 (t 0..63 in flight) ----
    {
        const int b = s * 4 + half;
        const float* src = pre + (size_t)b * (T_SZ * NPRE) + pt * 128 + p_loc;
        issue_x(src, 0, 32, x0);
        __builtin_amdgcn_sched_barrier(0);
        issue_x(src, 32, 32, x1);
        __builtin_amdgcn_sched_barrier(0);
    }

#pragma unroll
    for (int r = 0; r < 2; ++r) {
        const int b_scan = s * 4 + 2 * r + half;
        const float* src = pre + (size_t)b_scan * (T_SZ * NPRE) + pt * 128 + p_loc;
        float carry = 0.0f;

        // consume t0..31 while t32..63 in flight
        consume16(x0, carry, &pk[0], decay);
        // issue t64..99 (36 loads)
        issue_x(src, 64, 36, x2);
        __builtin_amdgcn_sched_barrier(0);
        // consume t32..63 while t64..99 in flight
        consume16(x1, carry, &pk[16], decay);
        // issue B loads for phase lh=0 (batch 2r+0)
        load_B(post + (size_t)(s * 4 + 2 * r) * (T_SZ * NPOST) + qt * 128 + qloc,
               half, xb);
        __builtin_amdgcn_sched_barrier(0);
        // consume t64..95 and tail t96..99
        consume16(x2, carry, &pk[32], decay);
#pragma unroll
        for (int j = 0; j < 2; ++j) {
            uint32_t lo = bf16_rne(carry);
            carry = decay * (carry + x2[32 + 2 * j]);
            uint32_t hi = bf16_rne(carry);
            carry = decay * (carry + x2[32 + 2 * j + 1]);
            pk[48 + j] = lo | (hi << 16);
        }

        // ---- phase 0 (batch 2r+0) ----
        if (half == 0) deposit_A(A_lds, pk, pg, lp);
        store_B(B_lds, half, qg, q15, xb);
        __syncthreads();

        // issue B loads for phase 1 (batch 2r+1): in flight across MFMA0
        load_B(post + (size_t)(s * 4 + 2 * r + 1) * (T_SZ * NPOST) + qt * 128 + qloc,
               half, xb);
        __builtin_amdgcn_sched_barrier(0);

#pragma unroll
        for (int kc = 0; kc < 4; ++kc) {
            bf16x8 a[2], bb[8];
#pragma unroll
            for (int f = 0; f < 2; ++f)
                a[f] = *(const bf16x8*)&A_lds[kc * 8 + wave * 2 + f][lane * 8];
#pragma unroll
            for (int g = 0; g < 8; ++g)
                bb[g] = *(const bf16x8*)&B_lds[kc * 8 + g][lane * 8];
#pragma unroll
            for (int f = 0; f < 2; ++f)
#pragma unroll
                for (int g = 0; g < 8; ++g)
                    acc[f][g] = __builtin_amdgcn_mfma_f32_16x16x32_bf16(
                        a[f], bb[g], acc[f][g], 0, 0, 0);
        }
        __syncthreads();

        // ---- phase 1 (batch 2r+1) ----
        if (half == 1) deposit_A(A_lds, pk, pg, lp);
        store_B(B_lds, half, qg, q15, xb);
        __syncthreads();

        // prefetch round 1's scan loads: in flight across MFMA1
        if (r == 0) {
            const int bn = s * 4 + 2 + half;
            const float* srcn = pre + (size_t)bn * (T_SZ * NPRE) + pt * 128 + p_loc;
            issue_x(srcn, 0, 32, x0);
            __builtin_amdgcn_sched_barrier(0);
            issue_x(srcn, 32, 32, x1);
            __builtin_amdgcn_sched_barrier(0);
        }

#pragma unroll
        for (int kc = 0; kc < 4; ++kc) {
            bf16x8 a[2], bb[8];
#pragma unroll
            for (int f = 0; f < 2; ++f)
                a[f] = *(const bf16x8*)&A_lds[kc * 8 + wave * 2 + f][lane * 8];
#pragma unroll
            for (int g = 0; g < 8; ++g)
                bb[g] = *(const bf16x8*)&B_lds[kc * 8 + g][lane * 8];
#pragma unroll
            for (int f = 0; f < 2; ++f)
#pragma unroll
                for (int g = 0; g < 8; ++g)
                    acc[f][g] = __builtin_amdgcn_mfma_f32_16x16x32_bf16(
                        a[f], bb[g], acc[f][g], 0, 0, 0);
        }
        __syncthreads();
    }

    // ---- writeout: partial[bx][p_loc 128][q_loc 128]
    // C/D layout (m89/m91): col = lane&15, row = (lane>>4)*4 + reg
    float* pout = partial + (size_t)bx * (128 * 128);
#pragma unroll
    for (int f = 0; f < 2; ++f) {
        int r0 = wave * 32 + f * 16 + l4 * 4;
#pragma unroll
        for (int g = 0; g < 8; ++g) {
            int c = g * 16 + l15;
#pragma unroll
            for (int v = 0; v < 4; ++v)
                pout[(size_t)(r0 + v) * 128 + c] = acc[f][g][v];
        }
    }
}

// ---------------------------------------------------------------------------
// Reduce stage 1 (R10-proven): partial[bx = tile*128 + s][i], i = p*128+q.
// 2048 blocks x 256 thr; thread t: g = t>>16 (0..7), e = t&65535,
// tile = e>>14; sums s = g*16..+15 (4 indep chains).
// ---------------------------------------------------------------------------
__global__ __launch_bounds__(256) void stdp_reduce1(
    const float* __restrict__ partial, float* __restrict__ tmp)
{
    const int t = blockIdx.x * 256 + threadIdx.x;  // 0..524287
    const int g = t >> 16;                         // 0..7
    const int e = t & 65535;
    const int tile = e >> 14;
    const float* src = partial + ((size_t)(tile * 128 + g * 16) << 14) + (e & 16383);
    float a4[4] = {};
#pragma unroll
    for (int i = 0; i < 4; ++i)
#pragma unroll
        for (int u = 0; u < 4; ++u)
            a4[u] += src[(size_t)(u * 4 + i) << 14];
    tmp[t] = (a4[0] + a4[1]) + (a4[2] + a4[3]);
}

// ---------------------------------------------------------------------------
// Reduce stage 2 (R10-proven): 8 -> 1, un-tile, scale by (A+ - A-)/(B*T).
// ---------------------------------------------------------------------------
__global__ __launch_bounds__(256) void stdp_reduce2(
    const float* __restrict__ tmp, float* __restrict__ out)
{
    const int idx = blockIdx.x * 256 + threadIdx.x;  // 0..65535
    const int P = idx >> 8, Q = idx & 255;
    const int tile = (Q >> 7) * 2 + (P >> 7);
    const int e = (tile << 14) | ((P & 127) << 7) | (Q & 127);
    float a[4];
#pragma unroll
    for (int u = 0; u < 4; ++u)
        a[u] = tmp[(size_t)(2 * u) * 65536 + e] +
               tmp[(size_t)(2 * u + 1) * 65536 + e];
    const float scale = (0.005f - 0.00525f) * (1.0f / (float)KTOT);
    out[idx] = ((a[0] + a[1]) + (a[2] + a[3])) * scale;
}

// ---------------------------------------------------------------------------
extern "C" void kernel_launch(void* const* d_in, const int* in_sizes, int n_in,
                              void* d_out, int out_size, void* d_ws, size_t ws_size,
                              hipStream_t stream)
{
    const float* pre  = (const float*)d_in[0];   // [512,100,256]
    const float* post = (const float*)d_in[1];   // [512,100,256]
    float* out = (float*)d_out;                  // [256,256]

    // ws: partial 33.5 MB | tmp 2 MB
    float* partial = (float*)d_ws;
    float* tmp     = (float*)((char*)d_ws + (size_t)33554432);

    stdp_fused_gemm<<<512, 256, 0, stream>>>(pre, post, partial);
    stdp_reduce1<<<2048, 256, 0, stream>>>(partial, tmp);
    stdp_reduce2<<<256, 256, 0, stream>>>(tmp, out);
}

// Round 5
// 145.333 us; speedup vs baseline: 1.3081x; 1.3081x over previous
//
#include <hip/hip_runtime.h>
#include <stdint.h>

// Problem constants (from reference)
#define B_SZ   512
#define T_SZ   100
#define NPRE   256
#define NPOST  256
#define KTOT   (B_SZ * T_SZ)   // 51200

typedef __bf16 bf16x8 __attribute__((ext_vector_type(8)));
typedef float  floatx4 __attribute__((ext_vector_type(4)));

__device__ __forceinline__ uint32_t bf16_rne(float v) {
    uint32_t bits = __float_as_uint(v);
    return (bits + 0x7FFFu + ((bits >> 16) & 1u)) >> 16;
}
__device__ __forceinline__ uint32_t pack_trunc2(float a, float b) {
    return (__float_as_uint(a) >> 16) | (__float_as_uint(b) & 0xFFFF0000u);
}

// Async 16B global->LDS (no VGPR staging, vmcnt-counted).
__device__ __forceinline__ void async_ld16(float* lds, const float* g) {
    __builtin_amdgcn_global_load_lds(
        (const __attribute__((address_space(1))) unsigned int*)g,
        (__attribute__((address_space(3))) unsigned int*)lds,
        16, 0, 0);
}

// ---------------------------------------------------------------------------
// R16: DMA-staged pipeline (T3+T4), register-free staging.
// Evidence: R15 proved VGPR staging can't go deep (spill at 178 MB scratch
// but still 3.4 TB/s -> request-limited, not BW-limited). global_load_lds
// gives deep in-flight staging with zero VGPRs; counted vmcnt(3) + raw
// s_barrier (NOT __syncthreads: its vmcnt(0) drain kills the pipeline).
//
// 256 blocks x 1024 thr (16 waves, 1 block/CU; LDS 120 KB).
// Block bx: s = bx&127 (batches 4s..4s+3), pt = bx>>7 (p-half). C half-tile
// 128p x 256q; partial 33.5 MB. post is read by both pt-blocks (bx, bx+128:
// same XCD mod 8 -> L2/L3 absorbs the duplicate).
//
// 16 phases: chunk ck = bi*4+cc (batch bi, 32-t chunk cc). Raw fp32 tiles
// DMA'd row-major (perfectly coalesced, 1KB/instr): rawA[2][32][128],
// rawB[2][32][256], double-buffered. Per chunk per wave: 3 DMA instrs
// (1 A-rowpair + 2 B-rows). Phase k:
//   s_waitcnt vmcnt(3) (k=15: 0) ; s_barrier      <- chunk k landed, k+1 flying
//   convert: tid<128: scan p-col (carry in reg, bit-exact R8 fp32+RNE
//            sequence, t ascending across phases), deposit Afrag;
//            tid 128..639: pack B -> Bfrag (trunc exact for {0,1})
//   s_waitcnt lgkmcnt(0) ; s_barrier              <- frags visible
//   issue DMA chunk k+2 -> raw[k&1]               <- raw[k&1] now free
//   MFMA (8 per wave: 2 a-frags x 4 b-frags)
//   s_barrier                                     <- frag reads done before
//                                                    next convert overwrite
// Tail chunks (cc==3): rows clamped to t 96..99 (duplicate identical DMA
// writes, benign); convert zero-fills t>=100 so Bfrag pad is exact zero.
// Fragment LDS layouts identical to R10 (proven 0-conflict, proven C/D map).
// ---------------------------------------------------------------------------
__device__ __forceinline__ void issue_chunk(
    const float* __restrict__ pre, const float* __restrict__ post,
    int b0, int pt, int wave, int lane,
    float* rawA_buf /*[32][128]*/, float* rawB_buf /*[32][256]*/, int ck)
{
    const int bi = ck >> 2, cc = ck & 3;
    const float* pa = pre  + (size_t)(b0 + bi) * (T_SZ * NPRE)
                           + (size_t)(cc * 32) * NPRE + pt * 128;
    const float* pb = post + (size_t)(b0 + bi) * (T_SZ * NPOST)
                           + (size_t)(cc * 32) * NPOST;
    // A: 1 instr covers rows 2rp,2rp+1 (rows are 128 fl = 512 B contiguous
    // in LDS; per-lane global addr bridges the 256-fl global row stride)
    {
        const int rp = (cc < 3) ? wave : (wave < 1 ? wave : 1);
        const float* g = pa + (size_t)(2 * rp + (lane >> 5)) * NPRE + (lane & 31) * 4;
        async_ld16(rawA_buf + 2 * rp * 128, g);
    }
    // B: 2 instrs, rows wave, wave+16 (256 fl = 1 KB = one instr)
#pragma unroll
    for (int h = 0; h < 2; ++h) {
        const int r  = wave + 16 * h;
        const int rr = (cc < 3) ? r : (r < 3 ? r : 3);
        const float* g = pb + (size_t)rr * NPOST + lane * 4;
        async_ld16(rawB_buf + rr * 256, g);
    }
}

__global__ __launch_bounds__(1024) __attribute__((amdgpu_waves_per_eu(4, 4)))
void stdp_fused_gemm(
    const float* __restrict__ pre, const float* __restrict__ post,
    float* __restrict__ partial)
{
    __shared__ __align__(16) float rawA[2][32][128];            // 32 KB
    __shared__ __align__(16) float rawB[2][32][256];            // 64 KB
    __shared__ __align__(16) unsigned short Afrag[8][512];      //  8 KB
    __shared__ __align__(16) unsigned short Bfrag[16][512];     // 16 KB

    const int bx   = blockIdx.x;                  // 0..255
    const int s    = bx & 127;
    const int pt   = bx >> 7;
    const int tid  = threadIdx.x;                 // 0..1023
    const int lane = tid & 63, wave = tid >> 6;   // wave 0..15
    const int l15 = lane & 15, l4 = lane >> 4;
    const int b0 = s * 4;

    const float decay = 0.95122942450071400910f;  // expf(-1/20)

    floatx4 acc[2][4] = {};
    float carry = 0.0f;                           // scan state (tid<128)

    // ---- prologue: chunks 0,1 in flight ----
    issue_chunk(pre, post, b0, pt, wave, lane,
                &rawA[0][0][0], &rawB[0][0][0], 0);
    issue_chunk(pre, post, b0, pt, wave, lane,
                &rawA[1][0][0], &rawB[1][0][0], 1);
    __builtin_amdgcn_sched_barrier(0);

    // ---- 16 phases ----
#pragma unroll
    for (int k = 0; k < 16; ++k) {
        const int cb = k & 1;
        const int cc = k & 3;

        // chunk k landed (own DMAs per-wave), chunk k+1 stays in flight
        if (k < 15) asm volatile("s_waitcnt vmcnt(3)" ::: "memory");
        else        asm volatile("s_waitcnt vmcnt(0)" ::: "memory");
        __builtin_amdgcn_sched_barrier(0);
        __builtin_amdgcn_s_barrier();

        // ---- convert raw[cb] -> frag ----
        if (tid < 128) {
            // scan thread: p column tid (global p = pt*128+tid)
            if (cc == 0) carry = 0.0f;
            const int p15 = tid & 15, pgq = tid >> 4;
#pragma unroll
            for (int w = 0; w < 4; ++w) {
                float xv[8];
#pragma unroll
                for (int j = 0; j < 8; ++j) {
                    const int tt = cc * 32 + w * 8 + j;   // compile-time guard
                    xv[j] = (tt < T_SZ) ? rawA[cb][w * 8 + j][tid] : 0.0f;
                }
                uint32_t u[4];
#pragma unroll
                for (int m = 0; m < 4; ++m) {
                    uint32_t lo = bf16_rne(carry);        // trace[t]=carry
                    carry = decay * (carry + xv[2 * m]);
                    uint32_t hi = bf16_rne(carry);
                    carry = decay * (carry + xv[2 * m + 1]);
                    u[m] = lo | (hi << 16);
                }
                *(uint4*)&Afrag[pgq][(w * 16 + p15) * 8] =
                    make_uint4(u[0], u[1], u[2], u[3]);
            }
        } else if (tid < 640) {
            const int idx = tid - 128, q = idx & 255, th = idx >> 8;
            const int q15 = q & 15, qgq = q >> 4;
#pragma unroll
            for (int w2 = 0; w2 < 2; ++w2) {
                const int w = th * 2 + w2;
                float yv[8];
#pragma unroll
                for (int j = 0; j < 8; ++j) {
                    const int tt = cc * 32 + w * 8 + j;
                    yv[j] = (tt < T_SZ) ? rawB[cb][w * 8 + j][q] : 0.0f;
                }
                uint32_t u[4];
#pragma unroll
                for (int m = 0; m < 4; ++m)
                    u[m] = pack_trunc2(yv[2 * m], yv[2 * m + 1]);
                *(uint4*)&Bfrag[qgq][(w * 16 + q15) * 8] =
                    make_uint4(u[0], u[1], u[2], u[3]);
            }
        }

        asm volatile("s_waitcnt lgkmcnt(0)" ::: "memory");
        __builtin_amdgcn_sched_barrier(0);
        __builtin_amdgcn_s_barrier();

        // raw[cb] free -> issue chunk k+2 (flies across MFMA + next phase)
        if (k < 14) {
            issue_chunk(pre, post, b0, pt, wave, lane,
                        &rawA[cb][0][0], &rawB[cb][0][0], k + 2);
            __builtin_amdgcn_sched_barrier(0);
        }

        // ---- MFMA: wave owns 32p x 64q; 2 a-frags x 4 b-frags ----
        {
            bf16x8 af[2], bf[4];
#pragma unroll
            for (int f = 0; f < 2; ++f)
                af[f] = *(const bf16x8*)&Afrag[(wave >> 2) * 2 + f][lane * 8];
#pragma unroll
            for (int g = 0; g < 4; ++g)
                bf[g] = *(const bf16x8*)&Bfrag[(wave & 3) * 4 + g][lane * 8];
#pragma unroll
            for (int f = 0; f < 2; ++f)
#pragma unroll
                for (int g = 0; g < 4; ++g)
                    acc[f][g] = __builtin_amdgcn_mfma_f32_16x16x32_bf16(
                        af[f], bf[g], acc[f][g], 0, 0, 0);
        }

        // frag reads consumed (compiler lgkm waits before MFMA) -> barrier
        // protects frag from phase k+1's convert overwrite
        if (k < 15) {
            __builtin_amdgcn_sched_barrier(0);
            __builtin_amdgcn_s_barrier();
        }
    }

    // ---- writeout: partial[bx][p 128][q 256] ----
    // C/D layout (m89/m91): col = lane&15, row = (lane>>4)*4 + reg
    float* pout = partial + (size_t)bx * (128 * 256);
#pragma unroll
    for (int f = 0; f < 2; ++f) {
        const int r0 = (wave >> 2) * 32 + f * 16 + l4 * 4;
#pragma unroll
        for (int g = 0; g < 4; ++g) {
            const int c = (wave & 3) * 64 + g * 16 + l15;
#pragma unroll
            for (int v = 0; v < 4; ++v)
                pout[(size_t)(r0 + v) * 256 + c] = acc[f][g][v];
        }
    }
}

// ---------------------------------------------------------------------------
// Reduce stage 1: partial[bx = pt*128 + s][p 128][q 256] -> tmp[8][65536].
// e = P*256+Q (P = pt*128+p). Thread t: g = t>>16, e = t&65535;
// sums s = g*16 .. g*16+15 (same 4-chain tree as R10: s-off = u*4+i).
// Coalesced: consecutive t -> consecutive addr.
// ---------------------------------------------------------------------------
__global__ __launch_bounds__(256) void stdp_reduce1(
    const float* __restrict__ partial, float* __restrict__ tmp)
{
    const int t = blockIdx.x * 256 + threadIdx.x;  // 0..524287
    const int g = t >> 16;                         // 0..7
    const int e = t & 65535;
    const float* src = partial + (size_t)(e >> 15) * 4194304 + (e & 32767)
                               + (size_t)(g * 16) * 32768;
    float a4[4] = {};
#pragma unroll
    for (int i = 0; i < 4; ++i)
#pragma unroll
        for (int u = 0; u < 4; ++u)
            a4[u] += src[(size_t)(u * 4 + i) * 32768];
    tmp[t] = (a4[0] + a4[1]) + (a4[2] + a4[3]);
}

// ---------------------------------------------------------------------------
// Reduce stage 2: 8 -> 1 (same tree as R10), scale by (A+ - A-)/(B*T).
// Plain e = P*256+Q layout (no untiling).
// ---------------------------------------------------------------------------
__global__ __launch_bounds__(256) void stdp_reduce2(
    const float* __restrict__ tmp, float* __restrict__ out)
{
    const int idx = blockIdx.x * 256 + threadIdx.x;  // 0..65535
    float a[4];
#pragma unroll
    for (int u = 0; u < 4; ++u)
        a[u] = tmp[(size_t)(2 * u) * 65536 + idx] +
               tmp[(size_t)(2 * u + 1) * 65536 + idx];
    const float scale = (0.005f - 0.00525f) * (1.0f / (float)KTOT);
    out[idx] = ((a[0] + a[1]) + (a[2] + a[3])) * scale;
}

// ---------------------------------------------------------------------------
extern "C" void kernel_launch(void* const* d_in, const int* in_sizes, int n_in,
                              void* d_out, int out_size, void* d_ws, size_t ws_size,
                              hipStream_t stream)
{
    const float* pre  = (const float*)d_in[0];   // [512,100,256]
    const float* post = (const float*)d_in[1];   // [512,100,256]
    float* out = (float*)d_out;                  // [256,256]

    // ws: partial 33.5 MB | tmp 2 MB
    float* partial = (float*)d_ws;
    float* tmp     = (float*)((char*)d_ws + (size_t)33554432);

    stdp_fused_gemm<<<256, 1024, 0, stream>>>(pre, post, partial);
    stdp_reduce1<<<2048, 256, 0, stream>>>(partial, tmp);
    stdp_reduce2<<<256, 256, 0, stream>>>(tmp, out);
}